// Round 2
// 123.826 us; speedup vs baseline: 1.0051x; 1.0051x over previous
//
#include <hip/hip_runtime.h>

// Problem: out[b,l,0] = dot(s_s[b,l,:], W[l,0,:]) + bias[l,0]
// B=256, L=700, D=1024, O=1.  All f32.
// Memory-bound: 734 MB compulsory s_s read. Achieved ceiling on this chip
// (fillBuffer dispatches in rocprof) = 6.4-6.7 TB/s -> roofline ~112-118 us.
//
// R2 change vs R1 (l-major, 124.5 us = 6.08 TB/s effective):
//  (a) b-major wave mapping: wave_id = b*700 + l. Consecutive waves read
//      consecutive 4 KB s_s rows -> each block streams a contiguous 16 KB,
//      grid walks s_s near-linearly -> DRAM page/bank locality.
//      W locality is NOT lost: W is 2.87 MB total < 4 MiB per-XCD L2, so it
//      stays L2-resident under any traversal order.
//  (b) nontemporal loads on s_s (zero-reuse stream) so the 734 MB stream
//      doesn't evict the W working set from L2.
// R3: compile fix — __builtin_nontemporal_load needs a NATIVE vector type
//     (ext_vector_type), not HIP_vector_type<float,4>.

#define B_DIM 256
#define L_DIM 700
#define D_DIM 1024

typedef float floatx4 __attribute__((ext_vector_type(4)));

__global__ __launch_bounds__(256, 8)
void summarizer_kernel(const float* __restrict__ s_s,
                       const float* __restrict__ W,
                       const float* __restrict__ bias,
                       float* __restrict__ out) {
    const int gtid    = blockIdx.x * blockDim.x + threadIdx.x;
    const int wave_id = gtid >> 6;          // one wave per (b,l) row
    const int lane    = threadIdx.x & 63;

    if (wave_id >= B_DIM * L_DIM) return;

    const int b = wave_id / L_DIM;          // b-major: consecutive waves share b
    const int l = wave_id - b * L_DIM;      // ... and walk l contiguously

    // s_s row for (b,l) is at linear offset wave_id * D -> fully linear stream.
    const floatx4* __restrict__ sp =
        reinterpret_cast<const floatx4*>(s_s + (size_t)wave_id * D_DIM);
    const floatx4* __restrict__ wp =
        reinterpret_cast<const floatx4*>(W + (size_t)l * D_DIM);

    float acc = 0.0f;
#pragma unroll
    for (int k = 0; k < 4; ++k) {
        const floatx4 sv = __builtin_nontemporal_load(&sp[lane + k * 64]);
        const floatx4 wv = wp[lane + k * 64];
        acc += sv.x * wv.x;
        acc += sv.y * wv.y;
        acc += sv.z * wv.z;
        acc += sv.w * wv.w;
    }

    // Wave-wide sum (width 64).
#pragma unroll
    for (int off = 32; off > 0; off >>= 1)
        acc += __shfl_xor(acc, off, 64);

    if (lane == 0)
        out[wave_id] = acc + bias[l];       // out[b*L + l] == out[wave_id]
}

extern "C" void kernel_launch(void* const* d_in, const int* in_sizes, int n_in,
                              void* d_out, int out_size, void* d_ws, size_t ws_size,
                              hipStream_t stream) {
    const float* s_s  = (const float*)d_in[0];  // [B, L, D]
    const float* W    = (const float*)d_in[1];  // [L, 1, D]
    const float* bias = (const float*)d_in[2];  // [L, 1]
    float* out        = (float*)d_out;          // [B, L, 1]

    const int total_waves  = B_DIM * L_DIM;       // 179200
    const int waves_per_bk = 256 / 64;            // 4
    const int grid         = (total_waves + waves_per_bk - 1) / waves_per_bk;

    summarizer_kernel<<<grid, 256, 0, stream>>>(s_s, W, bias, out);
}